// Round 6
// baseline (14252.744 us; speedup 1.0000x reference)
//
#include <hip/hip_runtime.h>
#include <math.h>

// LSTM_53171695124900: 2-layer LSTM, H=1024, I=64, O=2, T=4096.
// Round-16 = r15 resubmit (round-5 bench was an infra container failure,
// no kernel verdict) with hardening: guard limits reduced (tag polls
// 2^18, counter spins 2^19) so any protocol livelock terminates in
// seconds -> harness gets an absmax verdict instead of a watchdog kill.
// Structure (from r15): wave-specialized split, no hot-loop barriers.
//   R1 (waves 0-3): poll h1(s-1) tag s -> stage LDS -> W_hh1.h1 (pinned
//     f16x2 regs) + x.Wih1 -> 16-lane reduce -> publish h1(s) tag s+1.
//     Extra staging-only step s=TSTEPS feeds R2's last iteration.
//   R2 (waves 4-7): iteration t computes TIMESTEP t: poll h2(t-1) tag t,
//     stage; read h1(t) = staging of R1 step t+1 (bufH=(t+1)&1,
//     cnt1 >= 4(t+2)); W_ih2.h1 + W_hh2.h2 (LDS f16 weights) -> reduce ->
//     publish h2(t) tag t+1 (hist row t / fallback row t&1).
// Throttles: cons1 >= 4(s-2), cons1R >= 4(s-1), cons2 >= 4(t-1).
// Deadlock audit: R2 iter t <- R1 step t+1; R1 step s <- R2 iter s-3
// (strictly decreasing, acyclic); counter totals cover all waits.

#define HID 1024
#define DIN 64
#define TSTEPS 4096
#define NWG 256
#define TPB 512

typedef unsigned long long u64;
typedef unsigned int u32;
typedef _Float16 f16x2 __attribute__((ext_vector_type(2)));
typedef __fp16   g16x2 __attribute__((ext_vector_type(2)));

// ws layout in u64 (8B tagged entries):
//   [0, 1024)                 : h1 packed entries, 2 slots x 512
//                               (tag<<32 | f16x2 payload = elems 2q,2q+1)
//   [2048, 2048 + 4097*1024)  : h2 f32+tag entries; hist mode = row per
//                               timestep (row t = h2(t), tag t+1),
//                               fallback mode = rows (t & 1)
#define H2_OFF 2048
#define WS_NEED_U64 (2048ull + 4097ull * 1024ull)
#define WS_NEED_BYTES (WS_NEED_U64 * 8ull)
#define WS_ZERO_BYTES 32768

// dynamic LDS: 4096 uint4 f16 weights (64KB) + 2 x double-buffered stages
#define WLDS_U4 4096
#define H1S_OFF (WLDS_U4 * 16)                 // 65536 B
#define H2S_OFF (H1S_OFF + 2 * 640 * 4)        // +5120 B
#define DYN_LDS_BYTES (H2S_OFF + 2 * 640 * 4)  // 75776 B

// staging address: entry e -> 20*(e>>4) + (e&15)  (groups of 16 u32,
// stride 20 keeps uint4 reads 16B-aligned; conflicts <= 4-way)
#define ADR20(e) (20 * ((e) >> 4) + ((e) & 15))

#define POLL_GUARD (1 << 18)
#define SPIN_GUARD (1 << 19)

__device__ __forceinline__ float sigmoid_f(float v) {
    return 1.0f / (1.0f + __expf(-v));
}
__device__ __forceinline__ float tanh_f(float v) {
    return 2.0f / (1.0f + __expf(-2.0f * v)) - 1.0f;
}

// relaxed agent-scope 8B atomics: coherent at IC
__device__ __forceinline__ void st_u64(u64* p, u64 v) {
    __hip_atomic_store(p, v, __ATOMIC_RELAXED, __HIP_MEMORY_SCOPE_AGENT);
}
__device__ __forceinline__ void st_pair(u64* p, float h, u32 tag) {
    u64 pk = ((u64)tag << 32) | (u64)__float_as_uint(h);
    __hip_atomic_store(p, pk, __ATOMIC_RELAXED, __HIP_MEMORY_SCOPE_AGENT);
}
__device__ __forceinline__ u64 ld_pair(const u64* p) {
    return __hip_atomic_load(p, __ATOMIC_RELAXED, __HIP_MEMORY_SCOPE_AGENT);
}
#define PTAG(v) ((u32)((v) >> 32))
#define PVAL(v) (__uint_as_float((u32)(v)))

// LDS counter sync (workgroup scope, monotonic -> no ABA)
__device__ __forceinline__ void bump(int* c) {
    __hip_atomic_fetch_add(c, 1, __ATOMIC_RELEASE, __HIP_MEMORY_SCOPE_WORKGROUP);
}
__device__ __forceinline__ void spin_ge(int* c, int target) {
    int g = 0;
    while (__hip_atomic_load(c, __ATOMIC_ACQUIRE,
                             __HIP_MEMORY_SCOPE_WORKGROUP) < target) {
        if (++g > SPIN_GUARD) break;   // hang insurance only
    }
}

union U32H2 { u32 u; f16x2 h; g16x2 g; };
__device__ __forceinline__ u32 pk2(float a, float b) {
    U32H2 t; t.g = __builtin_amdgcn_cvt_pkrtz(a, b); return t.u;
}

#if defined(__has_builtin)
#if __has_builtin(__builtin_amdgcn_fdot2)
#define HAS_FDOT2 1
#endif
#endif
__device__ __forceinline__ float dot2f(u32 a, u32 b, float c) {
    U32H2 x, y; x.u = a; y.u = b;
#ifdef HAS_FDOT2
    return __builtin_amdgcn_fdot2(x.h, y.h, c, false);
#else
    float r = fmaf((float)x.h.x, (float)y.h.x, c);
    return fmaf((float)x.h.y, (float)y.h.y, r);
#endif
}

__device__ __forceinline__ uint4 pack4(float4 a, float4 b) {
    return make_uint4(pk2(a.x, a.y), pk2(a.z, a.w),
                      pk2(b.x, b.y), pk2(b.z, b.w));
}

#define PIN8() asm volatile("" : "+v"(qw0.x), "+v"(qw0.y), "+v"(qw0.z), \
    "+v"(qw0.w), "+v"(qw1.x), "+v"(qw1.y), "+v"(qw1.z), "+v"(qw1.w),    \
    "+v"(qw2.x), "+v"(qw2.y), "+v"(qw2.z), "+v"(qw2.w),                 \
    "+v"(qw3.x), "+v"(qw3.y), "+v"(qw3.z), "+v"(qw3.w));                \
    asm volatile("" : "+v"(qw4.x), "+v"(qw4.y), "+v"(qw4.z),            \
    "+v"(qw4.w), "+v"(qw5.x), "+v"(qw5.y), "+v"(qw5.z), "+v"(qw5.w),    \
    "+v"(qw6.x), "+v"(qw6.y), "+v"(qw6.z), "+v"(qw6.w),                 \
    "+v"(qw7.x), "+v"(qw7.y), "+v"(qw7.z), "+v"(qw7.w))

__global__ void
__attribute__((amdgpu_flat_work_group_size(TPB, TPB), amdgpu_waves_per_eu(2, 2)))
lstm_persistent(
    const float* __restrict__ x,
    const float* __restrict__ Wih1, const float* __restrict__ Whh1,
    const float* __restrict__ bih1, const float* __restrict__ bhh1,
    const float* __restrict__ Wih2, const float* __restrict__ Whh2,
    const float* __restrict__ bih2, const float* __restrict__ bhh2,
    const float* __restrict__ Wout, const float* __restrict__ bout,
    float* __restrict__ out, u64* __restrict__ ws, int use_hist)
{
    const int wg   = blockIdx.x;          // 0..255
    const int tid  = threadIdx.x;         // 0..511
    const int half = tid >> 8;            // 0 = R1 (layer1), 1 = R2 (layer2)
    const int rt   = tid & 255;           // index within half
    const int rrow = rt >> 4;             // 0..15 (= gate*4 + unit)
    const int cc   = rt & 15;             // k-chunk 0..15 (64 elems each)
    const int gate = rrow >> 2;
    const int rs   = rrow & 3;
    const int R    = gate * HID + (wg << 2) + rs;  // global gate-row

    u64* h1t = ws;
    u64* h2t = ws + H2_OFF;

    extern __shared__ __align__(16) char smem[];
    uint4* wlds = (uint4*)smem;                  // 64KB f16 weights (R2)
    u32*   h1s  = (u32*)(smem + H1S_OFF);        // 2 x 640 u32
    u32*   h2s  = (u32*)(smem + H2S_OFF);        // 2 x 640 u32

    __shared__ float g1buf[2][16], g2buf[2][16];
    __shared__ float red0[8], red1[8];
    __shared__ float redF0[2][4], redF1[2][4];
    __shared__ int cnt1, cnt1g, cons1, cons1R, cnt2, cnt2g, cons2, cntO;

    if (tid == 0) {
        cnt1 = 0; cnt1g = 0; cons1 = 0; cons1R = 0;
        cnt2 = 0; cnt2g = 0; cons2 = 0; cntO = 0;
    }

    // ---- R2 one-time: stage Wih2/Whh2 chunks into LDS as packed f16 ----
    if (half == 1) {
        const float4* q2 = (const float4*)(Wih2 + (size_t)R * HID + (cc << 6));
        const float4* q3 = (const float4*)(Whh2 + (size_t)R * HID + (cc << 6));
        #pragma unroll
        for (int j = 0; j < 8; ++j)
            wlds[(j << 8) + rt] = pack4(q2[2*j], q2[2*j+1]);
        #pragma unroll
        for (int j = 0; j < 8; ++j)
            wlds[2048 + (j << 8) + rt] = pack4(q3[2*j], q3[2*j+1]);
    }
    __syncthreads();   // counters zeroed + wlds staged (only barrier pre-epilogue)

    if (half == 0) {
        // ================= R1: layer-1 ring =================
        // step s (0..TSTEPS): poll h1(s-1) tag s, stage; if s<TSTEPS:
        // compute timestep s, publish h1(s) tag s+1. Step TSTEPS is
        // staging-only (feeds R2's last iteration).
        const float4* p1 = (const float4*)(Whh1 + (size_t)R * HID + (cc << 6));
        uint4 qw0 = pack4(p1[0],  p1[1]);
        uint4 qw1 = pack4(p1[2],  p1[3]);
        uint4 qw2 = pack4(p1[4],  p1[5]);
        uint4 qw3 = pack4(p1[6],  p1[7]);
        uint4 qw4 = pack4(p1[8],  p1[9]);
        uint4 qw5 = pack4(p1[10], p1[11]);
        uint4 qw6 = pack4(p1[12], p1[13]);
        uint4 qw7 = pack4(p1[14], p1[15]);
        PIN8();
        const float4 wx4 = *(const float4*)(Wih1 + (size_t)R * DIN + (cc << 2));
        const float bs1 = bih1[R] + bhh1[R];
        float cA = 0.f, cB = 0.f;    // c1 state (threads 0,1 only)

        for (int s = 0; s <= TSTEPS; ++s) {
            const int buf = s & 1;
            u32* hb = h1s + buf * 640;

            // buffer-reuse throttles:
            //   cons1:  R2 read staging(s-2) at its iter s-3
            //   cons1R: R1 waves' own reads of buffer at step s-2
            if (s >= 3) spin_ge(&cons1, 4*(s-2));
            if (s >= 2) spin_ge(&cons1R, 4*(s-1));

            // poll h1(s-1), tag s (skip s=0: zero initial state)
            u32 pay1 = 0, pay2 = 0;
            if (s > 0) {
                const u64* hp = h1t + (size_t)buf * 512;
                const u32 want = (u32)s;
                u64 va = ld_pair(hp + rt), vb = ld_pair(hp + rt + 256);
                int guard = 0;
                while ((PTAG(va) != want) | (PTAG(vb) != want)) {
                    if (PTAG(va) != want) va = ld_pair(hp + rt);
                    if (PTAG(vb) != want) vb = ld_pair(hp + rt + 256);
                    if (++guard > POLL_GUARD) break;
                }
                pay1 = (u32)va; pay2 = (u32)vb;
            }

            hb[ADR20(rt)]       = pay1;
            hb[ADR20(rt) + 320] = pay2;
            asm volatile("s_waitcnt lgkmcnt(0)" ::: "memory");
            if ((rt & 63) == 0) bump(&cnt1);

            if (s == TSTEPS) break;   // staging-only final step

            spin_ge(&cnt1, 4*(s+1));
            const float4 xv4 = *(const float4*)(x + (size_t)s * DIN + (cc << 2));

            // A-dots: W_hh1 . h1(s-1) from regs
            float a0 = 0.f, a1 = 0.f;
            {
                const u32* hbb = hb + 40 * cc;
                uint4 hv;
                hv = *(const uint4*)(hbb + 0);
                a0 = dot2f(hv.x, qw0.x, a0); a1 = dot2f(hv.y, qw0.y, a1);
                a0 = dot2f(hv.z, qw0.z, a0); a1 = dot2f(hv.w, qw0.w, a1);
                hv = *(const uint4*)(hbb + 4);
                a0 = dot2f(hv.x, qw1.x, a0); a1 = dot2f(hv.y, qw1.y, a1);
                a0 = dot2f(hv.z, qw1.z, a0); a1 = dot2f(hv.w, qw1.w, a1);
                hv = *(const uint4*)(hbb + 8);
                a0 = dot2f(hv.x, qw2.x, a0); a1 = dot2f(hv.y, qw2.y, a1);
                a0 = dot2f(hv.z, qw2.z, a0); a1 = dot2f(hv.w, qw2.w, a1);
                hv = *(const uint4*)(hbb + 12);
                a0 = dot2f(hv.x, qw3.x, a0); a1 = dot2f(hv.y, qw3.y, a1);
                a0 = dot2f(hv.z, qw3.z, a0); a1 = dot2f(hv.w, qw3.w, a1);
                hv = *(const uint4*)(hbb + 20);
                a0 = dot2f(hv.x, qw4.x, a0); a1 = dot2f(hv.y, qw4.y, a1);
                a0 = dot2f(hv.z, qw4.z, a0); a1 = dot2f(hv.w, qw4.w, a1);
                hv = *(const uint4*)(hbb + 24);
                a0 = dot2f(hv.x, qw5.x, a0); a1 = dot2f(hv.y, qw5.y, a1);
                a0 = dot2f(hv.z, qw5.z, a0); a1 = dot2f(hv.w, qw5.w, a1);
                hv = *(const uint4*)(hbb + 28);
                a0 = dot2f(hv.x, qw6.x, a0); a1 = dot2f(hv.y, qw6.y, a1);
                a0 = dot2f(hv.z, qw6.z, a0); a1 = dot2f(hv.w, qw6.w, a1);
                hv = *(const uint4*)(hbb + 32);
                a0 = dot2f(hv.x, qw7.x, a0); a1 = dot2f(hv.y, qw7.y, a1);
                a0 = dot2f(hv.z, qw7.z, a0); a1 = dot2f(hv.w, qw7.w, a1);
            }
            asm volatile("s_waitcnt lgkmcnt(0)" ::: "memory");
            if ((rt & 63) == 0) bump(&cons1R);

            a0 = fmaf(wx4.x, xv4.x, a0); a1 = fmaf(wx4.y, xv4.y, a1);
            a0 = fmaf(wx4.z, xv4.z, a0); a1 = fmaf(wx4.w, xv4.w, a1);
            float accA = a0 + a1;
            accA += __shfl_xor(accA, 1);
            accA += __shfl_xor(accA, 2);
            accA += __shfl_xor(accA, 4);
            accA += __shfl_xor(accA, 8);
            if (cc == 0) {
                float vA = accA + bs1;
                g1buf[buf][rrow] = (gate == 2) ? tanh_f(vA) : sigmoid_f(vA);
            }
            asm volatile("s_waitcnt lgkmcnt(0)" ::: "memory");
            if ((rt & 63) == 0) bump(&cnt1g);

            if (rt < 2) {
                spin_ge(&cnt1g, 4*(s+1));
                const float* gb = g1buf[buf];
                const int u0 = rt << 1;
                float i0 = gb[u0],   fv0 = gb[4+u0], g0 = gb[8+u0],  o0 = gb[12+u0];
                float i1 = gb[u0+1], fv1 = gb[5+u0], g1x = gb[9+u0], o1 = gb[13+u0];
                cA = fv0 * cA + i0 * g0;
                cB = fv1 * cB + i1 * g1x;
                float h0  = o0 * tanh_f(cA);
                float h1v = o1 * tanh_f(cB);
                u64 pkv = ((u64)(u32)(s + 1) << 32) | (u64)pk2(h0, h1v);
                st_u64(h1t + (size_t)((s + 1) & 1) * 512 + (wg << 1) + rt, pkv);
            }
            PIN8();
        }
    } else {
        // ================= R2: layer-2 ring =================
        // iteration t (0..TSTEPS-1) computes TIMESTEP t:
        //   h2(t) = cell2(h1(t), h2(t-1));  h1(t) = staging of R1 step t+1.
        const float bs2 = bih2[R] + bhh2[R];
        float c2r = 0.f;   // rt<4 only
        const float2 wa0 = *(const float2*)(Wout + (rt << 1));
        const float2 wa1 = *(const float2*)(Wout + 512 + (rt << 1));
        const float2 wb0 = *(const float2*)(Wout + HID + (rt << 1));
        const float2 wb1 = *(const float2*)(Wout + HID + 512 + (rt << 1));

        for (int t = 0; t < TSTEPS; ++t) {
            const int bufK = t & 1;          // h2s / g2buf buffer
            const int bufH = (t + 1) & 1;    // h1 staging of R1 step t+1
            u32* h1b = h1s + bufH * 640;
            u32* h2b = h2s + bufK * 640;

            if (t >= 2) spin_ge(&cons2, 4*(t-1));

            // poll h2(t-1), tag t (skip t=0: zero initial state)
            float v0 = 0.f, v1 = 0.f, v2 = 0.f, v3 = 0.f;
            if (t > 0) {
                const u64* hp = h2t +
                    (size_t)(use_hist ? (t - 1) : ((t - 1) & 1)) * 1024;
                const u32 want = (u32)t;
                u64 a = ld_pair(hp + 2*rt),        b = ld_pair(hp + 2*rt + 1);
                u64 cq = ld_pair(hp + 2*rt + 512), d = ld_pair(hp + 2*rt + 513);
                int guard = 0;
                while ((PTAG(a) != want) | (PTAG(b) != want) |
                       (PTAG(cq) != want) | (PTAG(d) != want)) {
                    if (PTAG(a) != want)  a  = ld_pair(hp + 2*rt);
                    if (PTAG(b) != want)  b  = ld_pair(hp + 2*rt + 1);
                    if (PTAG(cq) != want) cq = ld_pair(hp + 2*rt + 512);
                    if (PTAG(d) != want)  d  = ld_pair(hp + 2*rt + 513);
                    if (++guard > POLL_GUARD) break;
                }
                v0 = PVAL(a); v1 = PVAL(b); v2 = PVAL(cq); v3 = PVAL(d);
            }

            h2b[ADR20(rt)]       = pk2(v0, v1);
            h2b[ADR20(rt) + 320] = pk2(v2, v3);
            asm volatile("s_waitcnt lgkmcnt(0)" ::: "memory");
            if ((rt & 63) == 0) bump(&cnt2);

            spin_ge(&cnt1, 4*(t+2));   // h1(t) staged by R1 step t+1
            spin_ge(&cnt2, 4*(t+1));   // h2 staged by all R2 waves

            float e0 = 0.f, e1 = 0.f;
            const u32* hA = h1b + 40 * cc;
            const u32* hB = h2b + 40 * cc;
            #pragma unroll
            for (int j = 0; j < 8; ++j) {
                const int off = 20 * (j >> 2) + 4 * (j & 3);
                uint4 hv = *(const uint4*)(hA + off);
                uint4 w2 = wlds[(j << 8) + rt];
                e0 = dot2f(hv.x, w2.x, e0); e1 = dot2f(hv.y, w2.y, e1);
                e0 = dot2f(hv.z, w2.z, e0); e1 = dot2f(hv.w, w2.w, e1);
            }
            #pragma unroll
            for (int j = 0; j < 8; ++j) {
                const int off = 20 * (j >> 2) + 4 * (j & 3);
                uint4 gv = *(const uint4*)(hB + off);
                uint4 w3 = wlds[2048 + (j << 8) + rt];
                e0 = dot2f(gv.x, w3.x, e0); e1 = dot2f(gv.y, w3.y, e1);
                e0 = dot2f(gv.z, w3.z, e0); e1 = dot2f(gv.w, w3.w, e1);
            }
            asm volatile("s_waitcnt lgkmcnt(0)" ::: "memory");
            if ((rt & 63) == 0) { bump(&cons1); bump(&cons2); }

            float accB = e0 + e1;
            accB += __shfl_xor(accB, 1);
            accB += __shfl_xor(accB, 2);
            accB += __shfl_xor(accB, 4);
            accB += __shfl_xor(accB, 8);
            if (cc == 0) {
                float vB = accB + bs2;
                g2buf[bufK][rrow] = (gate == 2) ? tanh_f(vB) : sigmoid_f(vB);
            }
            asm volatile("s_waitcnt lgkmcnt(0)" ::: "memory");
            if ((rt & 63) == 0) bump(&cnt2g);

            if (rt < 4) {
                spin_ge(&cnt2g, 4*(t+1));
                const float* gb = g2buf[bufK];
                float iv = gb[rt], fv = gb[4+rt], gv2 = gb[8+rt], ov = gb[12+rt];
                c2r = fv * c2r + iv * gv2;
                float hh = ov * tanh_f(c2r);
                const int wr = use_hist ? t : (t & 1);
                st_pair(h2t + (size_t)wr * 1024 + (wg << 2) + rt, hh, (u32)(t + 1));
            }

            // fallback out-path: out[t-1] from this iteration's h2(t-1) poll
            if (!use_hist && wg == 0 && t >= 1) {
                float q0 = wa0.x*v0 + wa0.y*v1 + wa1.x*v2 + wa1.y*v3;
                float q1 = wb0.x*v0 + wb0.y*v1 + wb1.x*v2 + wb1.y*v3;
                #pragma unroll
                for (int m = 1; m < 64; m <<= 1) {
                    q0 += __shfl_xor(q0, m);
                    q1 += __shfl_xor(q1, m);
                }
                const int wv = rt >> 6;
                if ((rt & 63) == 0) { redF0[bufK][wv] = q0; redF1[bufK][wv] = q1; }
                asm volatile("s_waitcnt lgkmcnt(0)" ::: "memory");
                if ((rt & 63) == 0) bump(&cntO);
                if (rt == 0) {
                    spin_ge(&cntO, 4*t);
                    float o0 = bout[0], o1 = bout[1];
                    #pragma unroll
                    for (int w = 0; w < 4; ++w) {
                        o0 += redF0[bufK][w]; o1 += redF1[bufK][w];
                    }
                    out[2*(t-1)+0] = o0;
                    out[2*(t-1)+1] = o1;
                }
            }
        }
    }

    __syncthreads();   // rejoin halves before epilogue

    // ---- epilogue ----
    if (use_hist) {
        const float2 wo0 = *(const float2*)(Wout + (tid << 1));
        const float2 wo1 = *(const float2*)(Wout + HID + (tid << 1));
        const float bo0 = bout[0], bo1 = bout[1];
        for (int i = 0; i < 16; ++i) {
            const int t = (wg << 4) + i;
            const u64* hp = h2t + (size_t)t * 1024 + (tid << 1);
            const u32 want = (u32)(t + 1);
            u64 va, vb; int guard = 0;
            for (;;) {
                va = ld_pair(hp); vb = ld_pair(hp + 1);
                if ((PTAG(va) == want) && (PTAG(vb) == want)) break;
                if (++guard > (1 << 15)) break;
            }
            float h0 = PVAL(va), h1v = PVAL(vb);
            float q0 = wo0.x * h0 + wo0.y * h1v;
            float q1 = wo1.x * h0 + wo1.y * h1v;
            #pragma unroll
            for (int m = 1; m < 64; m <<= 1) {
                q0 += __shfl_xor(q0, m);
                q1 += __shfl_xor(q1, m);
            }
            if ((tid & 63) == 0) { red0[tid >> 6] = q0; red1[tid >> 6] = q1; }
            __syncthreads();
            if (tid == 0) {
                float o0 = bo0, o1 = bo1;
                #pragma unroll
                for (int w = 0; w < 8; ++w) { o0 += red0[w]; o1 += red1[w]; }
                out[2*t+0] = o0;
                out[2*t+1] = o1;
            }
            __syncthreads();
        }
    } else if (wg == 0) {
        // final out[T-1]: fallback row (TSTEPS-1)&1 = 1, tag TSTEPS
        const float2 wo0 = *(const float2*)(Wout + (tid << 1));
        const float2 wo1 = *(const float2*)(Wout + HID + (tid << 1));
        const u64* hp = h2t + (size_t)((TSTEPS - 1) & 1) * 1024 + (tid << 1);
        const u32 want = (u32)TSTEPS;
        u64 va, vb; int guard = 0;
        for (;;) {
            va = ld_pair(hp); vb = ld_pair(hp + 1);
            if ((PTAG(va) == want) && (PTAG(vb) == want)) break;
            if (++guard > (1 << 15)) break;
        }
        float h0 = PVAL(va), h1v = PVAL(vb);
        float q0 = wo0.x * h0 + wo0.y * h1v;
        float q1 = wo1.x * h0 + wo1.y * h1v;
        #pragma unroll
        for (int m = 1; m < 64; m <<= 1) {
            q0 += __shfl_xor(q0, m);
            q1 += __shfl_xor(q1, m);
        }
        if ((tid & 63) == 0) { red0[tid >> 6] = q0; red1[tid >> 6] = q1; }
        __syncthreads();
        if (tid == 0) {
            float o0 = bout[0], o1 = bout[1];
            #pragma unroll
            for (int w = 0; w < 8; ++w) { o0 += red0[w]; o1 += red1[w]; }
            out[2*(TSTEPS-1)+0] = o0;
            out[2*(TSTEPS-1)+1] = o1;
        }
    }
}

extern "C" void kernel_launch(void* const* d_in, const int* in_sizes, int n_in,
                              void* d_out, int out_size, void* d_ws, size_t ws_size,
                              hipStream_t stream)
{
    const float* x    = (const float*)d_in[0];
    const float* Wih1 = (const float*)d_in[1];
    const float* Whh1 = (const float*)d_in[2];
    const float* bih1 = (const float*)d_in[3];
    const float* bhh1 = (const float*)d_in[4];
    const float* Wih2 = (const float*)d_in[5];
    const float* Whh2 = (const float*)d_in[6];
    const float* bih2 = (const float*)d_in[7];
    const float* bhh2 = (const float*)d_in[8];
    const float* Wout = (const float*)d_in[9];
    const float* bout = (const float*)d_in[10];
    float* out = (float*)d_out;
    u64*   ws  = (u64*)d_ws;

    const int use_hist = (ws_size >= WS_NEED_BYTES) ? 1 : 0;

    // allow >64KB dynamic LDS (idempotent, not stream-ordered: capture-safe)
    (void)hipFuncSetAttribute((const void*)lstm_persistent,
                              hipFuncAttributeMaxDynamicSharedMemorySize,
                              DYN_LDS_BYTES);

    // protocol no longer depends on zeroed rows (s=0/t=0 polls skipped),
    // but keep the memset as belt-and-braces
    (void)hipMemsetAsync(d_ws, 0, WS_ZERO_BYTES, stream);

    hipLaunchKernelGGL(lstm_persistent, dim3(NWG), dim3(TPB), DYN_LDS_BYTES,
                       stream,
                       x, Wih1, Whh1, bih1, bhh1,
                       Wih2, Whh2, bih2, bhh2,
                       Wout, bout, out, ws, use_hist);
}

// Round 7
// 7560.273 us; speedup vs baseline: 1.8852x; 1.8852x over previous
//
#include <hip/hip_runtime.h>
#include <math.h>

// LSTM_53171695124900: 2-layer LSTM, H=1024, I=64, O=2, T=4096.
// Persistent kernel, 256 WGs x 512 threads.
// Round-17 = RESTORE of the session-best verified kernel (round-0 state,
// r10 lineage; measured 7475-7581us, absmax 2.441e-4). Rounds 11-16
// falsified: IC congestion (r12: -19% traffic, 0% time), barrier vmcnt
// drains (r13), poll prefetch (r13), shallow wave-split decoupling
// (r16: depth-2 buffers re-serialize the rings through the cross-half
// throttle cycle R1(s) <- R2(s-3) <- R1(s-2), +13x LDS counter conflict
// overhead -> 14.25ms). The single-ring 3-barrier phase remains the
// empirical optimum; restoring it re-anchors the session.
// Structure: all-warp phase: poll h1 -> stage -> A-dot (W_hh1 regs +
// W_ih2 LDS) -> reduce -> g1 -> h2 residual poll + stage -> S2 ->
// EARLY h1 publish -> B-dot (W_hh2 LDS) -> reduce -> g2 -> S3 ->
// h2 publish (+out). All dot inputs f16 (v_dot2_f32_f16), f32 acc.

#define HID 1024
#define DIN 64
#define TSTEPS 4096
#define NWG 256
#define TPB 512

typedef unsigned long long u64;
typedef unsigned int u32;
typedef _Float16 f16x2 __attribute__((ext_vector_type(2)));
typedef __fp16   g16x2 __attribute__((ext_vector_type(2)));

// ws layout in u64 (8B tagged pairs):
//   [0, 2048)                 : h1 pairs, 2 slots x 1024
//   [2048, 2048 + 4097*1024)  : h2 pairs; hist mode = row per phase,
//                               fallback mode = rows (phase & 1)
#define H2_OFF 2048
#define WS_NEED_U64 (2048ull + 4097ull * 1024ull)
#define WS_NEED_BYTES (WS_NEED_U64 * 8ull)
#define WS_ZERO_BYTES 32768   // h1 slots (16KB) + h2 rows 0..1 (16KB)

// dynamic LDS: 8*512 uint4 f16 weights (64KB) + 2 x 640-u32 h staging
#define WLDS_U4 (8 * 512)
#define H1S_OFF (WLDS_U4 * 16)            // bytes
#define H2S_OFF (H1S_OFF + 640 * 4)
#define DYN_LDS_BYTES (H2S_OFF + 640 * 4) // 70656 B

__device__ __forceinline__ float sigmoid_f(float v) {
    return 1.0f / (1.0f + __expf(-v));
}
__device__ __forceinline__ float tanh_f(float v) {
    return 2.0f / (1.0f + __expf(-2.0f * v)) - 1.0f;
}

// relaxed agent-scope 8B atomics: coherent at IC, no cache-maintenance insts
__device__ __forceinline__ void st_pair(u64* p, float h, u32 tag) {
    u64 pk = ((u64)tag << 32) | (u64)__float_as_uint(h);
    __hip_atomic_store(p, pk, __ATOMIC_RELAXED, __HIP_MEMORY_SCOPE_AGENT);
}
__device__ __forceinline__ u64 ld_pair(const u64* p) {
    return __hip_atomic_load(p, __ATOMIC_RELAXED, __HIP_MEMORY_SCOPE_AGENT);
}
#define PTAG(v) ((u32)((v) >> 32))
#define PVAL(v) (__uint_as_float((u32)(v)))

// same 4 bytes seen as u32 / __fp16x2 (cvt_pkrtz) / _Float16x2 (fdot2)
union U32H2 { u32 u; f16x2 h; g16x2 g; };

// pack two f32 -> half2 u32 (v_cvt_pkrtz_f16_f32, single inst)
__device__ __forceinline__ u32 pk2(float a, float b) {
    U32H2 t; t.g = __builtin_amdgcn_cvt_pkrtz(a, b); return t.u;
}

#if defined(__has_builtin)
#if __has_builtin(__builtin_amdgcn_fdot2)
#define HAS_FDOT2 1
#endif
#endif

// f32 += half2 . half2  (v_dot2_f32_f16 when available)
__device__ __forceinline__ float dot2f(u32 a, u32 b, float c) {
    U32H2 x, y; x.u = a; y.u = b;
#ifdef HAS_FDOT2
    return __builtin_amdgcn_fdot2(x.h, y.h, c, false);
#else
    float r = fmaf((float)x.h.x, (float)y.h.x, c);
    return fmaf((float)x.h.y, (float)y.h.y, r);
#endif
}

#define PIN_W1() asm volatile("" : "+v"(w1p0), "+v"(w1p1), "+v"(w1p2), \
    "+v"(w1p3), "+v"(w1p4), "+v"(w1p5), "+v"(w1p6), "+v"(w1p7), \
    "+v"(w1p8), "+v"(w1p9), "+v"(w1pA), "+v"(w1pB), \
    "+v"(w1pC), "+v"(w1pD), "+v"(w1pE), "+v"(w1pF))

// A-step j (j=0..3): 8 h1 elems; W1 (reg half2s) -> accA, W2 (LDS) -> accB
#define ASTEP(j, P0, P1, P2, P3) do {                               \
    uint4 hv = *(const uint4*)(h1s + hbase + 4*(j));                \
    uint4 w2 = wlds[(j)*512 + tid];                                 \
    a0 = dot2f(hv.x, P0, a0); a1 = dot2f(hv.y, P1, a1);             \
    a0 = dot2f(hv.z, P2, a0); a1 = dot2f(hv.w, P3, a1);             \
    e0 = dot2f(hv.x, w2.x, e0); e1 = dot2f(hv.y, w2.y, e1);         \
    e0 = dot2f(hv.z, w2.z, e0); e1 = dot2f(hv.w, w2.w, e1);         \
} while (0)

// B-step j (j=0..3): 8 h2 elems; W3 (LDS) -> accB
#define BSTEP(j) do {                                               \
    uint4 gv = *(const uint4*)(h2s + hbase + 4*(j));                \
    uint4 w3 = wlds[(4+(j))*512 + tid];                             \
    e0 = dot2f(gv.x, w3.x, e0); e1 = dot2f(gv.y, w3.y, e1);         \
    e0 = dot2f(gv.z, w3.z, e0); e1 = dot2f(gv.w, w3.w, e1);         \
} while (0)

__global__ void
__attribute__((amdgpu_flat_work_group_size(TPB, TPB), amdgpu_waves_per_eu(2, 2)))
lstm_persistent(
    const float* __restrict__ x,
    const float* __restrict__ Wih1, const float* __restrict__ Whh1,
    const float* __restrict__ bih1, const float* __restrict__ bhh1,
    const float* __restrict__ Wih2, const float* __restrict__ Whh2,
    const float* __restrict__ bih2, const float* __restrict__ bhh2,
    const float* __restrict__ Wout, const float* __restrict__ bout,
    float* __restrict__ out, u64* __restrict__ ws, int use_hist)
{
    const int wg   = blockIdx.x;          // 0..255
    const int tid  = threadIdx.x;         // 0..511
    const int wave = tid >> 6;            // 0..7
    const int lane = tid & 63;
    const int gate = tid >> 7;            // 0..3 (i,f,g,o)
    const int rsub = (tid >> 5) & 3;      // local unit 0..3
    const int c    = tid & 31;            // k-chunk 0..31
    const int row  = gate * HID + (wg << 2) + rsub;   // gate row in [0,4096)
    const int kbase = c << 5;

    u64* h1t = ws;
    u64* h2t = ws + H2_OFF;

    // ---- dynamic LDS carve ----
    extern __shared__ __align__(16) char smem[];
    uint4* wlds = (uint4*)smem;                  // 64KB f16 weights
    u32*   h1s  = (u32*)(smem + H1S_OFF);        // 640 u32 (stride-20 rows)
    u32*   h2s  = (u32*)(smem + H2S_OFF);        // 640 u32

    // ---- one-time: stage W_ih2/W_hh2 rows into LDS as packed f16 ----
    {
        const float4* q2 = (const float4*)(Wih2 + (size_t)row * HID + kbase);
        const float4* q3 = (const float4*)(Whh2 + (size_t)row * HID + kbase);
        #pragma unroll
        for (int j = 0; j < 4; ++j) {
            float4 qa = q2[2*j], qb = q2[2*j+1];
            wlds[j * 512 + tid] = make_uint4(pk2(qa.x, qa.y), pk2(qa.z, qa.w),
                                             pk2(qb.x, qb.y), pk2(qb.z, qb.w));
        }
        #pragma unroll
        for (int j = 0; j < 4; ++j) {
            float4 qa = q3[2*j], qb = q3[2*j+1];
            wlds[(4+j) * 512 + tid] = make_uint4(pk2(qa.x, qa.y), pk2(qa.z, qa.w),
                                                 pk2(qb.x, qb.y), pk2(qb.z, qb.w));
        }
    }

    // ---- W_hh1 row chunk: 16 packed-half2 u32 registers ----
    const float4* p1 = (const float4*)(Whh1 + (size_t)row * HID + kbase);
    float4 f0 = p1[0], f1 = p1[1], f2 = p1[2], f3 = p1[3];
    float4 f4 = p1[4], f5 = p1[5], f6 = p1[6], f7 = p1[7];
    u32 w1p0 = pk2(f0.x, f0.y), w1p1 = pk2(f0.z, f0.w);
    u32 w1p2 = pk2(f1.x, f1.y), w1p3 = pk2(f1.z, f1.w);
    u32 w1p4 = pk2(f2.x, f2.y), w1p5 = pk2(f2.z, f2.w);
    u32 w1p6 = pk2(f3.x, f3.y), w1p7 = pk2(f3.z, f3.w);
    u32 w1p8 = pk2(f4.x, f4.y), w1p9 = pk2(f4.z, f4.w);
    u32 w1pA = pk2(f5.x, f5.y), w1pB = pk2(f5.z, f5.w);
    u32 w1pC = pk2(f6.x, f6.y), w1pD = pk2(f6.z, f6.w);
    u32 w1pE = pk2(f7.x, f7.y), w1pF = pk2(f7.z, f7.w);
    PIN_W1();

    const float2 wx = *(const float2*)(Wih1 + (size_t)row * DIN + (c << 1));
    const float bsum1 = bih1[row] + bhh1[row];
    const float bsum2 = bih2[row] + bhh2[row];

    __shared__ float g1[4][4], g2[4][4];
    __shared__ float c1s[4], c2s[4];
    __shared__ float red0[8], red1[8];
    if (tid < 4) { c1s[tid] = 0.0f; c2s[tid] = 0.0f; }

    // h staging: chunk rows of 16 half2-u32 + 4 pad (stride 20 u32, 80B)
    const int sdst = 20 * (tid >> 4) + (tid & 15);
    const int hbase = 20 * c;

    __syncthreads();   // wlds staged, c-state zeroed

    for (int p = 0; p <= TSTEPS; ++p) {
        const u64* h1p = h1t + (size_t)(p & 1) * 1024 + (tid << 1);
        const int h2row_c = (p > 0) ? (use_hist ? (p - 1) : ((p - 1) & 1)) : 0;
        const u64* h2p = h2t + (size_t)h2row_c * 1024 + (tid << 1);
        const u32 want1 = (u32)p;
        const u32 want2 = (p >= 2) ? (u32)p : 0u;

        const int tx = (p < TSTEPS) ? p : 0;
        const float2 xv = *(const float2*)(x + (size_t)tx * DIN + (c << 1));

        // ---- blocking poll: h1(p-1), tag p (published mid-phase p-1) ----
        u64 v1a, v1b;
        {
            int guard = 0;
            for (;;) {
                v1a = ld_pair(h1p); v1b = ld_pair(h1p + 1);
                if ((PTAG(v1a) == want1) & (PTAG(v1b) == want1)) break;
                if (++guard > (1 << 17)) break;  // hang insurance only
            }
        }
        // early h2 read attempt (verified after the A-dot)
        u64 v2a = ld_pair(h2p), v2b = ld_pair(h2p + 1);

        PIN_W1();   // keepalive: W1 VGPR-resident every phase

        h1s[sdst] = pk2(PVAL(v1a), PVAL(v1b));
        __syncthreads();   // S1: h1s staged

        // ---- A-dot: accA = W_hh1.h1 (+x); accB partial = W_ih2.h1 ----
        float a0 = 0.f, a1 = 0.f, e0 = 0.f, e1 = 0.f;
        ASTEP(0, w1p0, w1p1, w1p2, w1p3);
        ASTEP(1, w1p4, w1p5, w1p6, w1p7);
        ASTEP(2, w1p8, w1p9, w1pA, w1pB);
        ASTEP(3, w1pC, w1pD, w1pE, w1pF);
        a0 = fmaf(wx.x, xv.x, a0);
        a1 = fmaf(wx.y, xv.y, a1);

        float accA = a0 + a1;
        accA += __shfl_xor(accA, 1);
        accA += __shfl_xor(accA, 2);
        accA += __shfl_xor(accA, 4);
        accA += __shfl_xor(accA, 8);
        accA += __shfl_xor(accA, 16);
        if (c == 0) {
            float vA = accA + bsum1;
            g1[gate][rsub] = (gate == 2) ? tanh_f(vA) : sigmoid_f(vA);
        }

        // ---- finish h2 poll (usually already satisfied) + stage ----
        {
            int guard = 0;
            while (!((PTAG(v2a) == want2) & (PTAG(v2b) == want2))) {
                v2a = ld_pair(h2p); v2b = ld_pair(h2p + 1);
                if (++guard > (1 << 17)) break;  // hang insurance only
            }
        }
        float sb0 = PVAL(v2a), sb1 = PVAL(v2b);
        h2s[sdst] = pk2(sb0, sb1);
        __syncthreads();   // S2: g1 + h2s ready

        // ---- EARLY h1 publication: before the heavy B-part ----
        if (p < TSTEPS && tid < 4) {
            float iv = g1[0][tid], fv = g1[1][tid];
            float gv = g1[2][tid], ov = g1[3][tid];
            float cn = fv * c1s[tid] + iv * gv;
            c1s[tid] = cn;
            st_pair(h1t + (size_t)((p + 1) & 1) * 1024 + (wg << 2) + tid,
                    ov * tanh_f(cn), (u32)(p + 1));
        }

        // ---- B-dot: accB += W_hh2.h2 ----
        BSTEP(0); BSTEP(1); BSTEP(2); BSTEP(3);

        float accB = e0 + e1;
        accB += __shfl_xor(accB, 1);
        accB += __shfl_xor(accB, 2);
        accB += __shfl_xor(accB, 4);
        accB += __shfl_xor(accB, 8);
        accB += __shfl_xor(accB, 16);
        if (c == 0) {
            float vB = accB + bsum2;
            g2[gate][rsub] = (gate == 2) ? tanh_f(vB) : sigmoid_f(vB);
        }
        __syncthreads();   // S3: g2 ready; also fences LDS reuse next phase

        if (p >= 1 && tid >= 4 && tid < 8) {
            int u = tid - 4;
            float iv = g2[0][u], fv = g2[1][u];
            float gv = g2[2][u], ov = g2[3][u];
            float cn = fv * c2s[u] + iv * gv;
            c2s[u] = cn;
            const int wr = use_hist ? p : (p & 1);
            st_pair(h2t + (size_t)wr * 1024 + (wg << 2) + u,
                    ov * tanh_f(cn), (u32)(p + 1));
        }

        // ---- fallback out-path (no hist workspace): WG0, out(p-2) ----
        if (!use_hist && wg == 0 && p >= 2) {
            const float2 wo0 = *(const float2*)(Wout + (tid << 1));
            const float2 wo1 = *(const float2*)(Wout + HID + (tid << 1));
            float q0 = wo0.x * sb0 + wo0.y * sb1;
            float q1 = wo1.x * sb0 + wo1.y * sb1;
            #pragma unroll
            for (int m = 1; m < 64; m <<= 1) {
                q0 += __shfl_xor(q0, m);
                q1 += __shfl_xor(q1, m);
            }
            if (lane == 0) { red0[wave] = q0; red1[wave] = q1; }
            __syncthreads();
            if (tid == 0) {
                float o0 = bout[0], o1 = bout[1];
                #pragma unroll
                for (int w = 0; w < 8; ++w) { o0 += red0[w]; o1 += red1[w]; }
                out[2*(p-2)+0] = o0;
                out[2*(p-2)+1] = o1;
            }
            __syncthreads();
        }
        // no grid barrier: next phase's poll is the synchronization
    }

    // ---- epilogue ----
    if (use_hist) {
        const float2 wo0 = *(const float2*)(Wout + (tid << 1));
        const float2 wo1 = *(const float2*)(Wout + HID + (tid << 1));
        const float bo0 = bout[0], bo1 = bout[1];
        for (int i = 0; i < 16; ++i) {
            const int t = (wg << 4) + i;
            const u64* hp = h2t + (size_t)(t + 1) * 1024 + (tid << 1);
            const u32 want = (u32)(t + 2);
            u64 va, vb; int guard = 0;
            for (;;) {
                va = ld_pair(hp); vb = ld_pair(hp + 1);
                if ((PTAG(va) == want) && (PTAG(vb) == want)) break;
                if (++guard > (1 << 15)) break;
            }
            float h0 = PVAL(va), h1v = PVAL(vb);
            float q0 = wo0.x * h0 + wo0.y * h1v;
            float q1 = wo1.x * h0 + wo1.y * h1v;
            #pragma unroll
            for (int m = 1; m < 64; m <<= 1) {
                q0 += __shfl_xor(q0, m);
                q1 += __shfl_xor(q1, m);
            }
            if (lane == 0) { red0[wave] = q0; red1[wave] = q1; }
            __syncthreads();
            if (tid == 0) {
                float o0 = bo0, o1 = bo1;
                #pragma unroll
                for (int w = 0; w < 8; ++w) { o0 += red0[w]; o1 += red1[w]; }
                out[2*t+0] = o0;
                out[2*t+1] = o1;
            }
            __syncthreads();
        }
    } else if (wg == 0) {
        // final out[T-1]: h2(T-1) written phase TSTEPS -> row TSTEPS&1 = 0,
        // tag TSTEPS+1
        const float2 wo0 = *(const float2*)(Wout + (tid << 1));
        const float2 wo1 = *(const float2*)(Wout + HID + (tid << 1));
        const u64* hp = h2t + (size_t)(TSTEPS & 1) * 1024 + (tid << 1);
        const u32 want = (u32)(TSTEPS + 1);
        u64 va, vb; int guard = 0;
        for (;;) {
            va = ld_pair(hp); vb = ld_pair(hp + 1);
            if ((PTAG(va) == want) && (PTAG(vb) == want)) break;
            if (++guard > (1 << 15)) break;
        }
        float h0 = PVAL(va), h1v = PVAL(vb);
        float q0 = wo0.x * h0 + wo0.y * h1v;
        float q1 = wo1.x * h0 + wo1.y * h1v;
        #pragma unroll
        for (int m = 1; m < 64; m <<= 1) {
            q0 += __shfl_xor(q0, m);
            q1 += __shfl_xor(q1, m);
        }
        if (lane == 0) { red0[wave] = q0; red1[wave] = q1; }
        __syncthreads();
        if (tid == 0) {
            float o0 = bout[0], o1 = bout[1];
            #pragma unroll
            for (int w = 0; w < 8; ++w) { o0 += red0[w]; o1 += red1[w]; }
            out[2*(TSTEPS-1)+0] = o0;
            out[2*(TSTEPS-1)+1] = o1;
        }
    }
}

extern "C" void kernel_launch(void* const* d_in, const int* in_sizes, int n_in,
                              void* d_out, int out_size, void* d_ws, size_t ws_size,
                              hipStream_t stream)
{
    const float* x    = (const float*)d_in[0];
    const float* Wih1 = (const float*)d_in[1];
    const float* Whh1 = (const float*)d_in[2];
    const float* bih1 = (const float*)d_in[3];
    const float* bhh1 = (const float*)d_in[4];
    const float* Wih2 = (const float*)d_in[5];
    const float* Whh2 = (const float*)d_in[6];
    const float* bih2 = (const float*)d_in[7];
    const float* bhh2 = (const float*)d_in[8];
    const float* Wout = (const float*)d_in[9];
    const float* bout = (const float*)d_in[10];
    float* out = (float*)d_out;
    u64*   ws  = (u64*)d_ws;

    const int use_hist = (ws_size >= WS_NEED_BYTES) ? 1 : 0;

    // allow >64KB dynamic LDS (idempotent, not stream-ordered: capture-safe)
    (void)hipFuncSetAttribute((const void*)lstm_persistent,
                              hipFuncAttributeMaxDynamicSharedMemorySize,
                              DYN_LDS_BYTES);

    // zero h1 slots + h2 rows 0..1 (ws re-poisoned 0xAA before every call;
    // poison can never equal a wanted tag, so un-zeroed hist rows are safe)
    (void)hipMemsetAsync(d_ws, 0, WS_ZERO_BYTES, stream);

    hipLaunchKernelGGL(lstm_persistent, dim3(NWG), dim3(TPB), DYN_LDS_BYTES,
                       stream,
                       x, Wih1, Whh1, bih1, bhh1,
                       Wih2, Whh2, bih2, bhh2,
                       Wout, bout, out, ws, use_hist);
}